// Round 6
// baseline (92.832 us; speedup 1.0000x reference)
//
#include <hip/hip_runtime.h>
#include <math.h>

// Problem constants (from reference): B=4, S=4096, H=768, L=8, fp32.
constexpr int kB = 4, kS = 4096, kH = 768, kL = 8;
constexpr int kBS = kB * kS;                       // 16384 rows
constexpr size_t kLayerStride = (size_t)kBS * kH;  // floats between layers
constexpr float kInvSqrtH = 0.03608439182435161f;  // 1/sqrt(768)

// Clang ext-vector (NOT HIP_vector_type) — required by __builtin_nontemporal_*.
typedef float f32x4 __attribute__((ext_vector_type(4)));

// Fused qW kernel: qw[j] = (sum_i q[i]*W[i][j]) / sqrt(H), one dispatch.
// grid=96, block=256. Block b owns 8 j-columns; thread t: jj=t&7, ic=t>>3
// (32 i-chunks x 24). 96 blocks keeps the 2.4 MB W_key read spread across
// CUs (per-CU HBM wall ~10 B/cyc — R3 arithmetic). LDS reduce is
// conflict-free: writes are linear (addr=tid); read phase is stride-8 over
// 8 threads -> 8 distinct banks.
__global__ __launch_bounds__(256) void qw_fused_kernel(
        const float* __restrict__ Wk,
        const float* __restrict__ q,
        float* __restrict__ qw) {
    __shared__ float lds[32][8];
    const int tid = threadIdx.x;
    const int jj = tid & 7;
    const int ic = tid >> 3;            // 0..31
    const int j = blockIdx.x * 8 + jj;  // 0..767
    const int i0 = ic * 24;

    float s = 0.f;
#pragma unroll
    for (int k = 0; k < 24; ++k)
        s = fmaf(q[i0 + k], Wk[(size_t)(i0 + k) * kH + j], s);
    lds[ic][jj] = s;
    __syncthreads();

    if (tid < 8) {
        float acc = 0.f;
#pragma unroll
        for (int c = 0; c < 32; ++c) acc += lds[c][tid];
        qw[blockIdx.x * 8 + tid] = acc * kInvSqrtH;
    }
}

// Main fused kernel: one 64-lane wave per (b,s) row.
// R6 single-change ablation vs R5: row loads are PLAIN (was NT). Everything
// else identical — NT stores kept, qv loaded inside the c-loop (R4 showed
// hoisting it costs 5.5us via the 128-VGPR cliff), __launch_bounds__(256,4).
__global__ __launch_bounds__(256, 4) void attn_fused_kernel(
        const float* __restrict__ pre,
        const float* __restrict__ qw,
        float* __restrict__ out) {
    const int wid = threadIdx.x >> 6;
    const int lane = threadIdx.x & 63;
    const int bs = blockIdx.x * 4 + wid;

    const f32x4* __restrict__ row =
        reinterpret_cast<const f32x4*>(pre) + (size_t)bs * (kH / 4);
    const f32x4* __restrict__ qw4 = reinterpret_cast<const f32x4*>(qw);

    // P1 — all row loads in flight (24 KB/wave outstanding). PLAIN loads.
    f32x4 v[kL][3];
#pragma unroll
    for (int l = 0; l < kL; ++l) {
        const f32x4* p = row + (size_t)l * (kLayerStride / 4);
#pragma unroll
        for (int c = 0; c < 3; ++c)
            v[l][c] = p[c * 64 + lane];
    }

    // P2 — per-lane partial dots.
    float d[kL];
#pragma unroll
    for (int l = 0; l < kL; ++l) d[l] = 0.f;
#pragma unroll
    for (int c = 0; c < 3; ++c) {
        const f32x4 qv = qw4[c * 64 + lane];  // L2-broadcast, one live at a time
#pragma unroll
        for (int l = 0; l < kL; ++l) {
            d[l] = fmaf(v[l][c].x, qv.x, d[l]);
            d[l] = fmaf(v[l][c].y, qv.y, d[l]);
            d[l] = fmaf(v[l][c].z, qv.z, d[l]);
            d[l] = fmaf(v[l][c].w, qv.w, d[l]);
        }
    }

    // P3 — butterfly reduce: all 64 lanes end with full per-layer dots.
#pragma unroll
    for (int off = 32; off > 0; off >>= 1) {
#pragma unroll
        for (int l = 0; l < kL; ++l) d[l] += __shfl_xor(d[l], off, 64);
    }

    // Softmax over L=8 (lane-local, identical in all lanes).
    float m = d[0];
#pragma unroll
    for (int l = 1; l < kL; ++l) m = fmaxf(m, d[l]);
    float sum = 0.f;
#pragma unroll
    for (int l = 0; l < kL; ++l) { d[l] = __expf(d[l] - m); sum += d[l]; }
    const float inv = 1.f / sum;
#pragma unroll
    for (int l = 0; l < kL; ++l) d[l] *= inv;

    // P4 — weighted sum + coalesced NT store.
    f32x4* __restrict__ o4 =
        reinterpret_cast<f32x4*>(out) + (size_t)bs * (kH / 4);
#pragma unroll
    for (int c = 0; c < 3; ++c) {
        f32x4 o = {0.f, 0.f, 0.f, 0.f};
#pragma unroll
        for (int l = 0; l < kL; ++l) {
            o.x = fmaf(d[l], v[l][c].x, o.x);
            o.y = fmaf(d[l], v[l][c].y, o.y);
            o.z = fmaf(d[l], v[l][c].z, o.z);
            o.w = fmaf(d[l], v[l][c].w, o.w);
        }
        __builtin_nontemporal_store(o, o4 + c * 64 + lane);
    }
}

extern "C" void kernel_launch(void* const* d_in, const int* in_sizes, int n_in,
                              void* d_out, int out_size, void* d_ws, size_t ws_size,
                              hipStream_t stream) {
    // setup_inputs order: 0=current_output (UNUSED by reference), 1=preceding,
    // 2=W_key, 3=query. All fp32.
    const float* pre = (const float*)d_in[1];
    const float* Wk  = (const float*)d_in[2];
    const float* q   = (const float*)d_in[3];
    float* out = (float*)d_out;

    // Workspace: qW [768 floats].
    float* qw = (float*)d_ws;

    qw_fused_kernel<<<kH / 8, 256, 0, stream>>>(Wk, q, qw);
    attn_fused_kernel<<<kBS / 4, 256, 0, stream>>>(pre, qw, out);
}

// Round 7
// 82.246 us; speedup vs baseline: 1.1287x; 1.1287x over previous
//
#include <hip/hip_runtime.h>
#include <math.h>

// Problem constants (from reference): B=4, S=4096, H=768, L=8, fp32.
constexpr int kB = 4, kS = 4096, kH = 768, kL = 8;
constexpr int kBS = kB * kS;                       // 16384 rows
constexpr size_t kLayerStride = (size_t)kBS * kH;  // floats between layers
constexpr float kInvSqrtH = 0.03608439182435161f;  // 1/sqrt(768)

// Clang ext-vector (NOT HIP_vector_type) — required by __builtin_nontemporal_*.
typedef float f32x4 __attribute__((ext_vector_type(4)));

// Fused qW kernel: qw[j] = (sum_i q[i]*W[i][j]) / sqrt(H), one dispatch.
// grid=96, block=256. Block b owns 8 j-columns; thread t: jj=t&7, ic=t>>3
// (32 i-chunks x 24). 96 blocks keeps the 2.4 MB W_key read spread across
// CUs (per-CU HBM wall ~10 B/cyc — R3 arithmetic). LDS reduce is
// conflict-free: writes are linear (addr=tid); read phase is stride-8 over
// 8 threads -> 8 distinct banks.
__global__ __launch_bounds__(256) void qw_fused_kernel(
        const float* __restrict__ Wk,
        const float* __restrict__ q,
        float* __restrict__ qw) {
    __shared__ float lds[32][8];
    const int tid = threadIdx.x;
    const int jj = tid & 7;
    const int ic = tid >> 3;            // 0..31
    const int j = blockIdx.x * 8 + jj;  // 0..767
    const int i0 = ic * 24;

    float s = 0.f;
#pragma unroll
    for (int k = 0; k < 24; ++k)
        s = fmaf(q[i0 + k], Wk[(size_t)(i0 + k) * kH + j], s);
    lds[ic][jj] = s;
    __syncthreads();

    if (tid < 8) {
        float acc = 0.f;
#pragma unroll
        for (int c = 0; c < 32; ++c) acc += lds[c][tid];
        qw[blockIdx.x * 8 + tid] = acc * kInvSqrtH;
    }
}

// Main fused kernel (R5-exact, measured 82.6us): one 64-lane wave per row.
//   P1: all 24 NT f32x4 row loads in flight (24 KB/wave in VGPRs).
//       NT load is worth 10.2us (R6 ablation) — zero-reuse stream must
//       bypass L2/L3 allocation.
//   P2: dots — qv loaded INSIDE the c-loop; hoisting it crosses the
//       128-VGPR cliff and costs 5.5us in spills (R4).
//   P3: butterfly reduce + lane-local softmax over L=8.
//   P4: weighted sum + NT store (out written once, never read).
__global__ __launch_bounds__(256, 4) void attn_fused_kernel(
        const float* __restrict__ pre,
        const float* __restrict__ qw,
        float* __restrict__ out) {
    const int wid = threadIdx.x >> 6;
    const int lane = threadIdx.x & 63;
    const int bs = blockIdx.x * 4 + wid;

    const f32x4* __restrict__ row =
        reinterpret_cast<const f32x4*>(pre) + (size_t)bs * (kH / 4);
    const f32x4* __restrict__ qw4 = reinterpret_cast<const f32x4*>(qw);

    // P1 — all row loads in flight (24 KB/wave outstanding).
    f32x4 v[kL][3];
#pragma unroll
    for (int l = 0; l < kL; ++l) {
        const f32x4* p = row + (size_t)l * (kLayerStride / 4);
#pragma unroll
        for (int c = 0; c < 3; ++c)
            v[l][c] = __builtin_nontemporal_load(p + c * 64 + lane);
    }

    // P2 — per-lane partial dots.
    float d[kL];
#pragma unroll
    for (int l = 0; l < kL; ++l) d[l] = 0.f;
#pragma unroll
    for (int c = 0; c < 3; ++c) {
        const f32x4 qv = qw4[c * 64 + lane];  // L2-broadcast, one live at a time
#pragma unroll
        for (int l = 0; l < kL; ++l) {
            d[l] = fmaf(v[l][c].x, qv.x, d[l]);
            d[l] = fmaf(v[l][c].y, qv.y, d[l]);
            d[l] = fmaf(v[l][c].z, qv.z, d[l]);
            d[l] = fmaf(v[l][c].w, qv.w, d[l]);
        }
    }

    // P3 — butterfly reduce: all 64 lanes end with full per-layer dots.
#pragma unroll
    for (int off = 32; off > 0; off >>= 1) {
#pragma unroll
        for (int l = 0; l < kL; ++l) d[l] += __shfl_xor(d[l], off, 64);
    }

    // Softmax over L=8 (lane-local, identical in all lanes).
    float m = d[0];
#pragma unroll
    for (int l = 1; l < kL; ++l) m = fmaxf(m, d[l]);
    float sum = 0.f;
#pragma unroll
    for (int l = 0; l < kL; ++l) { d[l] = __expf(d[l] - m); sum += d[l]; }
    const float inv = 1.f / sum;
#pragma unroll
    for (int l = 0; l < kL; ++l) d[l] *= inv;

    // P4 — weighted sum + coalesced NT store.
    f32x4* __restrict__ o4 =
        reinterpret_cast<f32x4*>(out) + (size_t)bs * (kH / 4);
#pragma unroll
    for (int c = 0; c < 3; ++c) {
        f32x4 o = {0.f, 0.f, 0.f, 0.f};
#pragma unroll
        for (int l = 0; l < kL; ++l) {
            o.x = fmaf(d[l], v[l][c].x, o.x);
            o.y = fmaf(d[l], v[l][c].y, o.y);
            o.z = fmaf(d[l], v[l][c].z, o.z);
            o.w = fmaf(d[l], v[l][c].w, o.w);
        }
        __builtin_nontemporal_store(o, o4 + c * 64 + lane);
    }
}

extern "C" void kernel_launch(void* const* d_in, const int* in_sizes, int n_in,
                              void* d_out, int out_size, void* d_ws, size_t ws_size,
                              hipStream_t stream) {
    // setup_inputs order: 0=current_output (UNUSED by reference), 1=preceding,
    // 2=W_key, 3=query. All fp32.
    const float* pre = (const float*)d_in[1];
    const float* Wk  = (const float*)d_in[2];
    const float* q   = (const float*)d_in[3];
    float* out = (float*)d_out;

    // Workspace: qW [768 floats].
    float* qw = (float*)d_ws;

    qw_fused_kernel<<<kH / 8, 256, 0, stream>>>(Wk, q, qw);
    attn_fused_kernel<<<kBS / 4, 256, 0, stream>>>(pre, qw, out);
}